// Round 2
// baseline (461.723 us; speedup 1.0000x reference)
//
#include <hip/hip_runtime.h>
#include <hip/hip_bf16.h>

// DCNv2 inception: 3 deformable convs (3x3 pad1, 5x5 pad2, 7x7 pad3),
// B=4, C=Co=64, H=W=64, fp32 in/out, outputs concat on channel dim (192 total).
//
// Strategy: channels-last transpose of x, bf16 weights in [k][o][c] layout,
// then one fused kernel: per 32-pixel tile, per tap k: bilinear-sample a
// bf16 A-tile (32 px x 64 ch, x mask) into LDS + stage 64x64 bf16 weight
// slice, then mfma_f32_16x16x32_bf16 accumulate (A: m=lane&15,k=quad*8+j;
// B from Wt[o][c]: n=lane&15,k=quad*8+j; D: col=lane&15,row=quad*4+reg).
//
// R1 fix: ALL four bilinear corners need full validity checks (y>=0 && y<H,
// x>=0 && x<W). y1/x1 can be negative when the offset pushes the tap far
// out-of-bounds (py < -1) -- reference zeroes those corners; we were
// including clamped border values. absmax 1.37 -> expected ~1e-2.

typedef __attribute__((ext_vector_type(8))) short bf16x8;
typedef __attribute__((ext_vector_type(4))) float f32x4;

#define LP 72  // LDS row pad (shorts): 144B rows -> balanced banks for b128 reads

__global__ void k_transpose_x(const float* __restrict__ x, float* __restrict__ xT) {
    int idx = blockIdx.x * 256 + threadIdx.x;      // 4*64*64*64 = 1048576 elems
    int c  = idx & 63;
    int wd = (idx >> 6) & 63;
    int h  = (idx >> 12) & 63;
    int b  = idx >> 18;
    xT[idx] = x[(((b * 64 + c) * 64 + h) * 64) + wd];
}

__global__ void k_prep_w(const float* __restrict__ f, unsigned short* __restrict__ wp, int K) {
    int idx = blockIdx.x * 256 + threadIdx.x;      // K*64*64 elems, [k][o][c]
    if (idx >= K * 4096) return;
    int c = idx & 63;
    int o = (idx >> 6) & 63;
    int k = idx >> 12;
    __hip_bfloat16 hb = __float2bfloat16(f[(o * 64 + c) * K + k]);
    wp[idx] = *reinterpret_cast<unsigned short*>(&hb);
}

__global__ __launch_bounds__(256) void k_dcn(
    const float* __restrict__ xT,
    const float* __restrict__ off1, const float* __restrict__ msk1, const unsigned short* __restrict__ wp1,
    const float* __restrict__ off2, const float* __restrict__ msk2, const unsigned short* __restrict__ wp2,
    const float* __restrict__ off3, const float* __restrict__ msk3, const unsigned short* __restrict__ wp3,
    float* __restrict__ out) {

    __shared__ __align__(16) unsigned short A_lds[2][32 * LP];
    __shared__ __align__(16) unsigned short W_lds[2][64 * LP];

    int bb     = blockIdx.x;
    int branch = bb % 3;          // interleave branches for load balance
    int tile   = bb / 3;          // 0..511
    int pixbase = tile * 32;
    int b  = pixbase >> 12;
    int h  = (pixbase >> 6) & 63;
    int w0 = pixbase & 63;        // 0 or 32

    const float* off; const float* msk; const unsigned short* wp;
    int K, kwid, pad, obase;
    if (branch == 0)      { off = off1; msk = msk1; wp = wp1; K = 9;  kwid = 3; pad = 1; obase = 0;   }
    else if (branch == 1) { off = off2; msk = msk2; wp = wp2; K = 25; kwid = 5; pad = 2; obase = 64;  }
    else                  { off = off3; msk = msk3; wp = wp3; K = 49; kwid = 7; pad = 3; obase = 128; }

    int tid  = threadIdx.x;
    int lane = tid & 63;
    int wv   = tid >> 6;          // wave 0..3
    int quad = lane >> 4;
    int l16  = lane & 15;

    // MFMA tile assignment: wave -> rowtile (16 pixels) x 2 coltiles (16 o each)
    int rowtile = wv & 1;
    int ct0     = (wv >> 1) * 2;

    f32x4 acc0 = {0.f, 0.f, 0.f, 0.f};
    f32x4 acc1 = {0.f, 0.f, 0.f, 0.f};

    // weight staging: thread -> o = tid>>2, 16 bf16 at col (tid&3)*16
    int wo  = tid >> 2;
    int wc0 = (tid & 3) * 16;

    const float* xbase = xT + (size_t)b * 64 * 64 * 64;

    int ky = 0, kx = 0;
    for (int k = 0; k < K; ++k) {
        int buf = k & 1;

        // ---- stage weight slice [64 o][64 c] bf16 for tap k ----
        {
            const uint4* src = reinterpret_cast<const uint4*>(wp + (k * 4096 + wo * 64 + wc0));
            uint4 wa = src[0];
            uint4 wb = src[1];
            uint4* dst = reinterpret_cast<uint4*>(&W_lds[buf][wo * LP + wc0]);
            dst[0] = wa;
            dst[1] = wb;
        }

        // ---- sample A-tile: 32 pixels x 64 channels, x mask, -> bf16 LDS ----
        int offy_base = ((b * 2 * K + 2 * k) * 64 + h) * 64 + w0;
        int offx_base = offy_base + 64 * 64;
        int msk_base  = ((b * K + k) * 64 + h) * 64 + w0;
        #pragma unroll
        for (int i = 0; i < 8; ++i) {
            int p  = wv + i * 4;          // 32 pixels across 4 waves
            float dy = off[offy_base + p];
            float dx = off[offx_base + p];
            float mk = msk[msk_base + p];
            float py = (float)(h - pad + ky) + dy;
            float px = (float)(w0 + p - pad + kx) + dx;
            float y0f = floorf(py), x0f = floorf(px);
            float wy = py - y0f,    wx = px - x0f;
            int y0 = (int)y0f, x0 = (int)x0f;
            int y1 = y0 + 1,   x1 = x0 + 1;
            int y0c = min(max(y0, 0), 63), y1c = min(max(y1, 0), 63);
            int x0c = min(max(x0, 0), 63), x1c = min(max(x1, 0), 63);
            float vy0 = (y0 >= 0 && y0 < 64) ? 1.f : 0.f;
            float vy1 = (y1 >= 0 && y1 < 64) ? 1.f : 0.f;
            float vx0 = (x0 >= 0 && x0 < 64) ? 1.f : 0.f;
            float vx1 = (x1 >= 0 && x1 < 64) ? 1.f : 0.f;
            float v00 = xbase[(y0c * 64 + x0c) * 64 + lane] * (vy0 * vx0);
            float v01 = xbase[(y0c * 64 + x1c) * 64 + lane] * (vy0 * vx1);
            float v10 = xbase[(y1c * 64 + x0c) * 64 + lane] * (vy1 * vx0);
            float v11 = xbase[(y1c * 64 + x1c) * 64 + lane] * (vy1 * vx1);
            float top = v00 + wx * (v01 - v00);
            float bot = v10 + wx * (v11 - v10);
            float s   = (top + wy * (bot - top)) * mk;
            __hip_bfloat16 hb = __float2bfloat16(s);
            A_lds[buf][p * LP + lane] = *reinterpret_cast<unsigned short*>(&hb);
        }

        __syncthreads();  // one barrier per tap (double-buffered LDS)

        // ---- MFMA: 2 K-chunks of 32, 2 coltiles per wave ----
        {
            int arow = rowtile * 16 + l16;
            #pragma unroll
            for (int c32 = 0; c32 < 2; ++c32) {
                bf16x8 af  = *reinterpret_cast<const bf16x8*>(&A_lds[buf][arow * LP + c32 * 32 + quad * 8]);
                bf16x8 bf0 = *reinterpret_cast<const bf16x8*>(&W_lds[buf][(ct0 * 16 + l16) * LP + c32 * 32 + quad * 8]);
                bf16x8 bf1 = *reinterpret_cast<const bf16x8*>(&W_lds[buf][((ct0 + 1) * 16 + l16) * LP + c32 * 32 + quad * 8]);
                acc0 = __builtin_amdgcn_mfma_f32_16x16x32_bf16(af, bf0, acc0, 0, 0, 0);
                acc1 = __builtin_amdgcn_mfma_f32_16x16x32_bf16(af, bf1, acc1, 0, 0, 0);
            }
        }

        if (++kx == kwid) { kx = 0; ++ky; }
    }

    // ---- epilogue: D col = lane&15 (o-within-tile), row = quad*4+reg (pixel) ----
    float* obp = out + (((size_t)b * 192 + obase) * 64 + h) * 64;
    int o0 = ct0 * 16 + l16;
    int o1 = (ct0 + 1) * 16 + l16;
    #pragma unroll
    for (int r = 0; r < 4; ++r) {
        int p   = rowtile * 16 + quad * 4 + r;
        int wxo = w0 + p;
        obp[o0 * 4096 + wxo] = acc0[r];
        obp[o1 * 4096 + wxo] = acc1[r];
    }
}

extern "C" void kernel_launch(void* const* d_in, const int* in_sizes, int n_in,
                              void* d_out, int out_size, void* d_ws, size_t ws_size,
                              hipStream_t stream) {
    const float* x    = (const float*)d_in[0];
    const float* f1   = (const float*)d_in[1];
    const float* off1 = (const float*)d_in[2];
    const float* msk1 = (const float*)d_in[3];
    const float* f2   = (const float*)d_in[4];
    const float* off2 = (const float*)d_in[5];
    const float* msk2 = (const float*)d_in[6];
    const float* f3   = (const float*)d_in[7];
    const float* off3 = (const float*)d_in[8];
    const float* msk3 = (const float*)d_in[9];
    float* out = (float*)d_out;

    // ws layout: xT (4 MB fp32) | wp1 (9*4096 bf16) | wp2 (25*4096) | wp3 (49*4096)
    float* xT = (float*)d_ws;
    unsigned short* wp1 = (unsigned short*)((char*)d_ws + 4194304);
    unsigned short* wp2 = wp1 + 9 * 4096;
    unsigned short* wp3 = wp2 + 25 * 4096;

    k_transpose_x<<<dim3(4096), dim3(256), 0, stream>>>(x, xT);
    k_prep_w<<<dim3(144), dim3(256), 0, stream>>>(f1, wp1, 9);
    k_prep_w<<<dim3(400), dim3(256), 0, stream>>>(f2, wp2, 25);
    k_prep_w<<<dim3(784), dim3(256), 0, stream>>>(f3, wp3, 49);
    k_dcn<<<dim3(1536), dim3(256), 0, stream>>>(xT,
                                                off1, msk1, wp1,
                                                off2, msk2, wp2,
                                                off3, msk3, wp3,
                                                out);
}

// Round 3
// 237.739 us; speedup vs baseline: 1.9421x; 1.9421x over previous
//
#include <hip/hip_runtime.h>
#include <hip/hip_bf16.h>

// DCNv2 inception, R3: barrier-free per-wave structure.
// - xTb: x transposed to channels-last [B][H][W][C] and cast to bf16 (prep).
// - wp:  weights bf16 in [k][o][c] (prep).
// - k_dcn: one wave (64-thr block) owns 16 pixels x 64 outputs. Per tap:
//   lane(l16,quad) computes params for pixel l16 (4x quad redundancy only),
//   gathers its A-fragment channels (quad*8+j) for 4 bilinear corners as
//   bf16x8 direct from global (no LDS, no barrier), lerps with 4 FMA/ch
//   (mask+validity folded into corner weights), packs to bf16 A-frags,
//   loads B-frags direct from wp (hot in L2), 8x mfma_16x16x32_bf16 into
//   4 accs. Epilogue: D col=lane&15 (o), row=quad*4+reg (pixel).

typedef __attribute__((ext_vector_type(8))) short bf16x8;
typedef __attribute__((ext_vector_type(8))) unsigned short u16x8;
typedef __attribute__((ext_vector_type(4))) float f32x4;

__device__ __forceinline__ float b2f(unsigned short u) {
    return __uint_as_float(((unsigned)u) << 16);
}
__device__ __forceinline__ unsigned short f2bf(float f) {
    __hip_bfloat16 h = __float2bfloat16(f);
    return *reinterpret_cast<unsigned short*>(&h);
}

// x[b][c][h][w] f32 -> xTb[b][h][w][c] bf16. One block per (b,h).
__global__ __launch_bounds__(256) void k_prep_x(const float* __restrict__ x,
                                                unsigned short* __restrict__ xTb) {
    __shared__ float tile[64][65];
    int b = blockIdx.x >> 6, h = blockIdx.x & 63;
    int tid = threadIdx.x;
    {
        int w = tid & 63, c4 = tid >> 6;
        const float* xp = x + (((b * 64) * 64 + h) * 64) + w;   // + c*4096
        #pragma unroll
        for (int i = 0; i < 16; ++i) {
            int c = c4 * 16 + i;
            tile[c][w] = xp[c * 4096];                          // coalesced 256B rows
        }
    }
    __syncthreads();
    {
        int c = tid & 63, w4 = tid >> 6;
        unsigned short* op = xTb + (((b * 64 + h) * 64) * 64) + c;  // + w*64
        #pragma unroll
        for (int i = 0; i < 16; ++i) {
            int ww = w4 * 16 + i;
            op[ww * 64] = f2bf(tile[c][ww]);                    // stride-65 LDS: conflict-free
        }
    }
}

// f[o][c][k] f32 -> wp[k][o][c] bf16, all three filters in one launch.
__global__ void k_prep_w(const float* __restrict__ f1, const float* __restrict__ f2,
                         const float* __restrict__ f3, unsigned short* __restrict__ wp1,
                         unsigned short* __restrict__ wp2, unsigned short* __restrict__ wp3) {
    int idx = blockIdx.x * 256 + threadIdx.x;   // 83*4096 = 339968 total
    const float* f; unsigned short* wp; int K, rel;
    if (idx < 36864)       { f = f1; wp = wp1; K = 9;  rel = idx; }
    else if (idx < 139264) { f = f2; wp = wp2; K = 25; rel = idx - 36864; }
    else                   { f = f3; wp = wp3; K = 49; rel = idx - 139264; }
    int c = rel & 63;
    int o = (rel >> 6) & 63;
    int k = rel >> 12;
    wp[rel] = f2bf(f[(o * 64 + c) * K + k]);
}

__global__ __launch_bounds__(64) void k_dcn(
    const unsigned short* __restrict__ xTb,
    const float* __restrict__ off1, const float* __restrict__ msk1, const unsigned short* __restrict__ wp1,
    const float* __restrict__ off2, const float* __restrict__ msk2, const unsigned short* __restrict__ wp2,
    const float* __restrict__ off3, const float* __restrict__ msk3, const unsigned short* __restrict__ wp3,
    float* __restrict__ out) {

    int bb     = blockIdx.x;
    int branch = bb % 3;
    int tile   = bb / 3;          // 0..1023, 16 pixels each
    int pix0   = tile << 4;
    int b  = pix0 >> 12;
    int h  = (pix0 >> 6) & 63;
    int w0 = pix0 & 63;           // 0,16,32,48

    const float* off; const float* msk; const unsigned short* wp;
    int K, kwid, pad, obase;
    if (branch == 0)      { off = off1; msk = msk1; wp = wp1; K = 9;  kwid = 3; pad = 1; obase = 0;   }
    else if (branch == 1) { off = off2; msk = msk2; wp = wp2; K = 25; kwid = 5; pad = 2; obase = 64;  }
    else                  { off = off3; msk = msk3; wp = wp3; K = 49; kwid = 7; pad = 3; obase = 128; }

    int lane = threadIdx.x & 63;
    int quad = lane >> 4;
    int l16  = lane & 15;
    int pw   = w0 + l16;          // this lane's pixel w-coordinate
    int ch0  = quad << 3;         // A-fragment channel base (k = quad*8+j)

    const unsigned short* xb = xTb + ((size_t)b << 18);
    const float* offy = off + (((b * 2 * K) * 64 + h) * 64) + pw;   // + k*8192
    const float* mskp = msk + (((b * K) * 64 + h) * 64) + pw;       // + k*4096

    f32x4 acc[4];
    #pragma unroll
    for (int i = 0; i < 4; ++i) acc[i] = (f32x4){0.f, 0.f, 0.f, 0.f};

    float fy  = (float)(h - pad);
    float fx0 = (float)(pw - pad);

    int ky = 0, kx = 0;
    for (int k = 0; k < K; ++k) {
        // ---- per-pixel params (lane owns pixel l16; 4x redundant over quads) ----
        float dy = offy[k * 8192];
        float dx = offy[k * 8192 + 4096];
        float mk = mskp[k * 4096];
        float py = fy + (float)ky + dy;
        float px = fx0 + (float)kx + dx;
        float y0f = floorf(py), x0f = floorf(px);
        float wy = py - y0f, wx = px - x0f;
        int y0 = (int)y0f, x0 = (int)x0f;
        int y1 = y0 + 1,   x1 = x0 + 1;
        int y0c = min(max(y0, 0), 63), y1c = min(max(y1, 0), 63);
        int x0c = min(max(x0, 0), 63), x1c = min(max(x1, 0), 63);
        float fy0 = ((unsigned)y0 < 64u) ? (1.f - wy) * mk : 0.f;
        float fy1 = ((unsigned)y1 < 64u) ? wy * mk        : 0.f;
        float gx0 = ((unsigned)x0 < 64u) ? (1.f - wx)     : 0.f;
        float gx1 = ((unsigned)x1 < 64u) ? wx             : 0.f;
        float w00 = fy0 * gx0, w01 = fy0 * gx1, w10 = fy1 * gx0, w11 = fy1 * gx1;

        int o00 = ((y0c << 6) + x0c) << 6;
        int o01 = ((y0c << 6) + x1c) << 6;
        int o10 = ((y1c << 6) + x0c) << 6;
        int o11 = ((y1c << 6) + x1c) << 6;

        // ---- A-fragment gathers: 8x dwordx4, no LDS round-trip ----
        u16x8 g00a = *(const u16x8*)(xb + o00 + ch0);
        u16x8 g01a = *(const u16x8*)(xb + o01 + ch0);
        u16x8 g10a = *(const u16x8*)(xb + o10 + ch0);
        u16x8 g11a = *(const u16x8*)(xb + o11 + ch0);
        u16x8 g00b = *(const u16x8*)(xb + o00 + 32 + ch0);
        u16x8 g01b = *(const u16x8*)(xb + o01 + 32 + ch0);
        u16x8 g10b = *(const u16x8*)(xb + o10 + 32 + ch0);
        u16x8 g11b = *(const u16x8*)(xb + o11 + 32 + ch0);

        // ---- bilinear lerp (4 FMA/ch) + pack to bf16 A-frags ----
        union { bf16x8 v; unsigned short u[8]; } A0, A1;
        #pragma unroll
        for (int j = 0; j < 8; ++j) {
            float s0 = w00 * b2f(g00a[j]) + w01 * b2f(g01a[j])
                     + w10 * b2f(g10a[j]) + w11 * b2f(g11a[j]);
            float s1 = w00 * b2f(g00b[j]) + w01 * b2f(g01b[j])
                     + w10 * b2f(g10b[j]) + w11 * b2f(g11b[j]);
            A0.u[j] = f2bf(s0);
            A1.u[j] = f2bf(s1);
        }

        // ---- B-fragments direct from global (hot in L2) + 8 MFMA ----
        const unsigned short* wpk = wp + (k << 12);
        #pragma unroll
        for (int ct = 0; ct < 4; ++ct) {
            const unsigned short* wr = wpk + ((ct * 16 + l16) << 6);
            bf16x8 b0 = *(const bf16x8*)(wr + ch0);
            bf16x8 b1 = *(const bf16x8*)(wr + 32 + ch0);
            acc[ct] = __builtin_amdgcn_mfma_f32_16x16x32_bf16(A0.v, b0, acc[ct], 0, 0, 0);
            acc[ct] = __builtin_amdgcn_mfma_f32_16x16x32_bf16(A1.v, b1, acc[ct], 0, 0, 0);
        }

        if (++kx == kwid) { kx = 0; ++ky; }
    }

    // ---- epilogue: D col=l16 -> o within tile, row=quad*4+r -> pixel ----
    float* obp = out + (((size_t)b * 192 + obase) * 64 + h) * 64;
    #pragma unroll
    for (int ct = 0; ct < 4; ++ct) {
        int o = ct * 16 + l16;
        #pragma unroll
        for (int r = 0; r < 4; ++r) {
            obp[o * 4096 + w0 + quad * 4 + r] = acc[ct][r];
        }
    }
}

extern "C" void kernel_launch(void* const* d_in, const int* in_sizes, int n_in,
                              void* d_out, int out_size, void* d_ws, size_t ws_size,
                              hipStream_t stream) {
    const float* x    = (const float*)d_in[0];
    const float* f1   = (const float*)d_in[1];
    const float* off1 = (const float*)d_in[2];
    const float* msk1 = (const float*)d_in[3];
    const float* f2   = (const float*)d_in[4];
    const float* off2 = (const float*)d_in[5];
    const float* msk2 = (const float*)d_in[6];
    const float* f3   = (const float*)d_in[7];
    const float* off3 = (const float*)d_in[8];
    const float* msk3 = (const float*)d_in[9];
    float* out = (float*)d_out;

    // ws: xTb (2 MB bf16) | wp1 (9*4096) | wp2 (25*4096) | wp3 (49*4096) bf16
    unsigned short* xTb = (unsigned short*)d_ws;
    unsigned short* wp1 = xTb + 4 * 64 * 64 * 64;
    unsigned short* wp2 = wp1 + 9 * 4096;
    unsigned short* wp3 = wp2 + 25 * 4096;

    k_prep_x<<<dim3(256), dim3(256), 0, stream>>>(x, xTb);
    k_prep_w<<<dim3(1328), dim3(256), 0, stream>>>(f1, f2, f3, wp1, wp2, wp3);
    k_dcn<<<dim3(3072), dim3(64), 0, stream>>>(xTb,
                                               off1, msk1, wp1,
                                               off2, msk2, wp2,
                                               off3, msk3, wp3,
                                               out);
}